// Round 3
// baseline (272.998 us; speedup 1.0000x reference)
//
#include <hip/hip_runtime.h>

#define TT 2048
#define DD 1024
#define HH 16
#define DKK 64
#define BB 2

typedef __attribute__((ext_vector_type(8))) short bf16x8;
typedef __attribute__((ext_vector_type(4))) float f32x4;
typedef __attribute__((ext_vector_type(4))) unsigned short us4;

__device__ __forceinline__ unsigned short f2bf(float f) {
  union { float f; unsigned int i; } v; v.f = f;
  unsigned int x = v.i;
  return (unsigned short)((x + 0x7fffu + ((x >> 16) & 1u)) >> 16);
}
__device__ __forceinline__ void gload16(const void* g, void* l) {
  __builtin_amdgcn_global_load_lds((const __attribute__((address_space(1))) void*)g,
                                   (__attribute__((address_space(3))) void*)l,
                                   16, 0, 0);
}

// fp32 -> bf16 (round-to-nearest-even), 4 elements/thread
__global__ __launch_bounds__(256)
void f2b_kernel(const float* __restrict__ in, unsigned short* __restrict__ out, int n4)
{
  int i = blockIdx.x * blockDim.x + threadIdx.x;
  const int stride = gridDim.x * blockDim.x;
  for (; i < n4; i += stride) {
    const float4 f = ((const float4*)in)[i];
    us4 o;
    o[0] = f2bf(f.x); o[1] = f2bf(f.y); o[2] = f2bf(f.z); o[3] = f2bf(f.w);
    ((us4*)out)[i] = o;
  }
}

// C = A @ W^T + bias, A:[4096][1024] bf16, W:[1024][1024] bf16 (row-major, n-major).
// MODE 0: bf16 out [4096][1024]
// MODE 1: V-transpose bf16 store: C is V_t[B][H][DK][T]
// MODE 2: fp32 out [4096][1024] (final projection -> d_out)
template<int MODE>
__global__ __launch_bounds__(256)
void gemm_bt(const unsigned short* __restrict__ A,
             const unsigned short* __restrict__ W,
             const float* __restrict__ bias,
             void* __restrict__ Cv, float scale)
{
  __shared__ unsigned short lA[2][128 * 32];
  __shared__ unsigned short lB[2][128 * 32];
  unsigned short* C = (unsigned short*)Cv;
  float* Cf = (float*)Cv;
  const int tid = threadIdx.x;
  const int w = tid >> 6, l = tid & 63;
  const int n0 = blockIdx.x * 128, m0 = blockIdx.y * 128;
  const int wr = w >> 1, wc = w & 1;
  const int lg = l >> 4, lc = l & 15;

  f32x4 acc[4][4];
#pragma unroll
  for (int i = 0; i < 4; ++i)
#pragma unroll
    for (int j = 0; j < 4; ++j) acc[i][j] = (f32x4){0.f, 0.f, 0.f, 0.f};

  const int scolb = (l & 3) * 16;  // 16B slot within a 64B LDS row

  auto stage = [&](int buf, int k0) {
#pragma unroll
    for (int cc = 0; cc < 2; ++cc) {
      const int slot = w * 2 + cc;           // 0..7, wave-uniform
      const int row = slot * 16 + (l >> 2);  // 0..127
      const unsigned short* ga = A + (size_t)(m0 + row) * DD + k0 + (scolb >> 1);
      const unsigned short* gw = W + (size_t)(n0 + row) * DD + k0 + (scolb >> 1);
      gload16(ga, &lA[buf][slot * 512]);
      gload16(gw, &lB[buf][slot * 512]);
    }
  };

  stage(0, 0);
  __syncthreads();
  int cur = 0;
#pragma unroll 1
  for (int kt = 0; kt < 32; ++kt) {
    if (kt < 31) stage(cur ^ 1, (kt + 1) * 32);
    bf16x8 af[4], bfr[4];
#pragma unroll
    for (int mf = 0; mf < 4; ++mf)
      af[mf] = *(const bf16x8*)&lA[cur][(wr * 64 + mf * 16 + lc) * 32 + lg * 8];
#pragma unroll
    for (int nf = 0; nf < 4; ++nf)
      bfr[nf] = *(const bf16x8*)&lB[cur][(wc * 64 + nf * 16 + lc) * 32 + lg * 8];
#pragma unroll
    for (int mf = 0; mf < 4; ++mf)
#pragma unroll
      for (int nf = 0; nf < 4; ++nf)
        acc[mf][nf] = __builtin_amdgcn_mfma_f32_16x16x32_bf16(af[mf], bfr[nf], acc[mf][nf], 0, 0, 0);
    __syncthreads();
    cur ^= 1;
  }

#pragma unroll
  for (int nf = 0; nf < 4; ++nf) {
    const int colg = n0 + wc * 64 + nf * 16 + lc;
    const float bv = bias[colg];
#pragma unroll
    for (int mf = 0; mf < 4; ++mf) {
      const int rowg = m0 + wr * 64 + mf * 16 + lg * 4;
      if (MODE == 0) {
#pragma unroll
        for (int r = 0; r < 4; ++r)
          C[(size_t)(rowg + r) * DD + colg] = f2bf(scale * (acc[mf][nf][r] + bv));
      } else if (MODE == 2) {
#pragma unroll
        for (int r = 0; r < 4; ++r)
          Cf[(size_t)(rowg + r) * DD + colg] = scale * (acc[mf][nf][r] + bv);
      } else {
        const int bb = rowg >> 11;          // row / T
        const int t = rowg & (TT - 1);      // row % T (4-aligned)
        const int hh = colg >> 6, dk = colg & 63;
        us4 pk;
#pragma unroll
        for (int r = 0; r < 4; ++r) pk[r] = f2bf(scale * (acc[mf][nf][r] + bv));
        *(us4*)&C[((size_t)((bb * HH + hh) * DKK + dk)) * TT + t] = pk;
      }
    }
  }
}

// Flash attention. Qp/Kp: [B*T][D] bf16 (Q pre-scaled by 1/8). Vt: [B*H*DK][T] bf16.
// Block: 64 q-rows (4 waves x 16). KV chunks of 64. Output Oc: [B*T][D] bf16.
__global__ __launch_bounds__(256)
void attn(const unsigned short* __restrict__ Qp,
          const unsigned short* __restrict__ Kp,
          const unsigned short* __restrict__ Vt,
          const int* __restrict__ maskp,
          const int* __restrict__ causalp,
          unsigned short* __restrict__ Oc)
{
  __shared__ unsigned short Kl[64 * 64];
  __shared__ unsigned short Vl[64 * 64];
  __shared__ unsigned short Pl[4][16 * 64];
  const int tid = threadIdx.x;
  const int w = tid >> 6, l = tid & 63;
  const int q0 = blockIdx.x * 64;
  const int b = blockIdx.y >> 4, h = blockIdx.y & 15;
  const int lg = l >> 4, lc = l & 15;
  const int causal = causalp[0];

  bf16x8 qf[2];
  {
    const int qr = q0 + w * 16 + lc;
    const unsigned short* qp = Qp + (size_t)(b * TT + qr) * DD + h * DKK + lg * 8;
    qf[0] = *(const bf16x8*)qp;
    qf[1] = *(const bf16x8*)(qp + 32);
  }
  f32x4 o[4];
#pragma unroll
  for (int nf = 0; nf < 4; ++nf) o[nf] = (f32x4){0.f, 0.f, 0.f, 0.f};
  float mr[4], lr[4];
#pragma unroll
  for (int r = 0; r < 4; ++r) { mr[r] = -1e30f; lr[r] = 0.f; }

  const int kvmax = causal ? (q0 + 64) : TT;
#pragma unroll 1
  for (int c0 = 0; c0 < kvmax; c0 += 64) {
    __syncthreads();  // prior-iteration LDS reads complete
#pragma unroll
    for (int cc = 0; cc < 2; ++cc) {
      const int slot = w * 2 + cc;          // wave-uniform
      const int rr = slot * 8 + (l >> 3);   // 0..63
      const int colb = (l & 7) * 16;        // 16B slot in 128B row
      const unsigned short* gk = Kp + (size_t)(b * TT + c0 + rr) * DD + h * DKK + (colb >> 1);
      gload16(gk, &Kl[slot * 512]);
      const unsigned short* gv = Vt + (size_t)((b * HH + h) * DKK + rr) * TT + c0 + (colb >> 1);
      gload16(gv, &Vl[slot * 512]);
    }
    __syncthreads();  // staging drained (vmcnt(0) before barrier)

    // S = Q K^T (Q already scaled by 1/sqrt(DK))
    f32x4 s[4];
#pragma unroll
    for (int nf = 0; nf < 4; ++nf) s[nf] = (f32x4){0.f, 0.f, 0.f, 0.f};
#pragma unroll
    for (int nf = 0; nf < 4; ++nf)
#pragma unroll
      for (int kk = 0; kk < 2; ++kk) {
        bf16x8 bfrag = *(const bf16x8*)&Kl[(nf * 16 + lc) * 64 + kk * 32 + lg * 8];
        s[nf] = __builtin_amdgcn_mfma_f32_16x16x32_bf16(qf[kk], bfrag, s[nf], 0, 0, 0);
      }

    // causal + padding mask
#pragma unroll
    for (int nf = 0; nf < 4; ++nf) {
      const int kg = c0 + nf * 16 + lc;
      const int mv = maskp[b * TT + kg];
#pragma unroll
      for (int r = 0; r < 4; ++r) {
        const int qg = q0 + w * 16 + lg * 4 + r;
        const bool dead = (mv == 0) || (causal && (kg > qg));
        if (dead) s[nf][r] = -1e30f;
      }
    }

    // online softmax: row max over 64 cols (4 frags x 16 lanes)
    float pm[4];
#pragma unroll
    for (int r = 0; r < 4; ++r)
      pm[r] = fmaxf(fmaxf(s[0][r], s[1][r]), fmaxf(s[2][r], s[3][r]));
#pragma unroll
    for (int mm = 1; mm < 16; mm <<= 1)
#pragma unroll
      for (int r = 0; r < 4; ++r)
        pm[r] = fmaxf(pm[r], __shfl_xor(pm[r], mm, 64));
    float al[4];
#pragma unroll
    for (int r = 0; r < 4; ++r) {
      const float mn = fmaxf(mr[r], pm[r]);
      al[r] = __expf(mr[r] - mn);
      mr[r] = mn;
    }
    float ps[4] = {0.f, 0.f, 0.f, 0.f};
#pragma unroll
    for (int nf = 0; nf < 4; ++nf)
#pragma unroll
      for (int r = 0; r < 4; ++r) {
        const float sv = s[nf][r];
        const float p = (sv <= -1e29f) ? 0.f : __expf(sv - mr[r]);
        ps[r] += p;
        Pl[w][(lg * 4 + r) * 64 + nf * 16 + lc] = f2bf(p);
      }
#pragma unroll
    for (int mm = 1; mm < 16; mm <<= 1)
#pragma unroll
      for (int r = 0; r < 4; ++r)
        ps[r] += __shfl_xor(ps[r], mm, 64);
#pragma unroll
    for (int r = 0; r < 4; ++r) lr[r] = lr[r] * al[r] + ps[r];
#pragma unroll
    for (int nf = 0; nf < 4; ++nf)
#pragma unroll
      for (int r = 0; r < 4; ++r) o[nf][r] *= al[r];
    __syncthreads();  // P visible; V staged

    // O += P @ V
    bf16x8 pa[2];
#pragma unroll
    for (int kk = 0; kk < 2; ++kk)
      pa[kk] = *(const bf16x8*)&Pl[w][lc * 64 + kk * 32 + lg * 8];
#pragma unroll
    for (int nf = 0; nf < 4; ++nf)
#pragma unroll
      for (int kk = 0; kk < 2; ++kk) {
        bf16x8 bfrag = *(const bf16x8*)&Vl[(nf * 16 + lc) * 64 + kk * 32 + lg * 8];
        o[nf] = __builtin_amdgcn_mfma_f32_16x16x32_bf16(pa[kk], bfrag, o[nf], 0, 0, 0);
      }
  }

#pragma unroll
  for (int nf = 0; nf < 4; ++nf) {
    const int dg = h * DKK + nf * 16 + lc;
#pragma unroll
    for (int r = 0; r < 4; ++r) {
      const int qg = q0 + w * 16 + lg * 4 + r;
      const float vv = o[nf][r] / lr[r];
      Oc[(size_t)(b * TT + qg) * DD + dg] = f2bf(vv);
    }
  }
}

extern "C" void kernel_launch(void* const* d_in, const int* in_sizes, int n_in,
                              void* d_out, int out_size, void* d_ws, size_t ws_size,
                              hipStream_t stream)
{
  (void)in_sizes; (void)n_in; (void)out_size; (void)ws_size;
  // Inputs fp32, output fp32 (reference dtypes).
  const float* kf = (const float*)d_in[0];
  const float* qf = (const float*)d_in[1];
  const float* vf = (const float*)d_in[2];
  const int* mask = (const int*)d_in[3];
  const int* causal = (const int*)d_in[4];
  const float* Wf = (const float*)d_in[5];
  const float* bf = (const float*)d_in[6];

  const size_t MB = 1024 * 1024;
  char* ws = (char*)d_ws;
  unsigned short* kb = (unsigned short*)(ws);                 // 8 MiB
  unsigned short* qb = (unsigned short*)(ws + 8 * MB);        // 8 MiB
  unsigned short* vb = (unsigned short*)(ws + 16 * MB);       // 8 MiB
  unsigned short* Wb = (unsigned short*)(ws + 24 * MB);       // 2 MiB
  unsigned short* Kp = (unsigned short*)(ws + 26 * MB);       // 8 MiB
  unsigned short* Qp = (unsigned short*)(ws + 34 * MB);       // 8 MiB
  unsigned short* Vt = (unsigned short*)(ws + 42 * MB);       // 8 MiB
  unsigned short* Oc = kb;  // kb is dead after the K projection

  const int nKQV = BB * TT * DD;   // 4.19M
  const int nW = DD * DD;          // 1.05M
  dim3 cb(256);
  f2b_kernel<<<dim3(2048), cb, 0, stream>>>(kf, kb, nKQV / 4);
  f2b_kernel<<<dim3(2048), cb, 0, stream>>>(qf, qb, nKQV / 4);
  f2b_kernel<<<dim3(2048), cb, 0, stream>>>(vf, vb, nKQV / 4);
  f2b_kernel<<<dim3(1024), cb, 0, stream>>>(Wf, Wb, nW / 4);

  dim3 gg(8, 32), blk(256);
  gemm_bt<0><<<gg, blk, 0, stream>>>(kb, Wb, bf, Kp, 1.0f);
  gemm_bt<0><<<gg, blk, 0, stream>>>(qb, Wb, bf, Qp, 0.125f);  // fold 1/sqrt(DK)
  gemm_bt<1><<<gg, blk, 0, stream>>>(vb, Wb, bf, Vt, 1.0f);    // store V transposed per head
  attn<<<dim3(32, 32), blk, 0, stream>>>(Qp, Kp, Vt, mask, causal, Oc);
  gemm_bt<2><<<gg, blk, 0, stream>>>(Oc, Wb, bf, d_out, 1.0f); // fp32 final output
}

// Round 4
// 165.175 us; speedup vs baseline: 1.6528x; 1.6528x over previous
//
#include <hip/hip_runtime.h>

#define TT 2048
#define DD 1024
#define HH 16
#define DKK 64
#define BB 2

typedef __attribute__((ext_vector_type(8))) short bf16x8;
typedef __attribute__((ext_vector_type(4))) short bf16x4;
typedef __attribute__((ext_vector_type(4))) float f32x4;
typedef __attribute__((ext_vector_type(4))) unsigned short us4;

__device__ __forceinline__ unsigned short f2bf(float f) {
  union { float f; unsigned int i; } v; v.f = f;
  unsigned int x = v.i;
  return (unsigned short)((x + 0x7fffu + ((x >> 16) & 1u)) >> 16);
}
__device__ __forceinline__ void gload16(const void* g, void* l) {
  __builtin_amdgcn_global_load_lds((const __attribute__((address_space(1))) void*)g,
                                   (__attribute__((address_space(3))) void*)l,
                                   16, 0, 0);
}

#if defined(__has_builtin)
#if __has_builtin(__builtin_amdgcn_mfma_f32_16x16x16bf16_1k)
#define HAVE_MFMA16 1
#endif
#endif

__device__ __forceinline__ f32x4 mfma16(bf16x4 a, bf16x4 b, f32x4 c) {
#ifdef HAVE_MFMA16
  return __builtin_amdgcn_mfma_f32_16x16x16bf16_1k(a, b, c, 0, 0, 0);
#else
  asm volatile("v_mfma_f32_16x16x16_bf16 %0, %1, %2, %0\n\ts_nop 7\n\ts_nop 7"
               : "+v"(c) : "v"(a), "v"(b));
  return c;
#endif
}

// fp32 -> bf16 for k,q,v,W in one dispatch
__global__ __launch_bounds__(256)
void f2b_all(const float* __restrict__ k, const float* __restrict__ q,
             const float* __restrict__ v, const float* __restrict__ W,
             unsigned short* __restrict__ kb, unsigned short* __restrict__ qb,
             unsigned short* __restrict__ vb, unsigned short* __restrict__ Wb)
{
  const int n1 = (BB * TT * DD) / 4;   // 1048576 float4s per tensor
  const int nW = (DD * DD) / 4;        // 262144
  const int total = 3 * n1 + nW;
  int i = blockIdx.x * 256 + threadIdx.x;
  const int stride = gridDim.x * 256;
  for (; i < total; i += stride) {
    const float* src; unsigned short* dst; int j = i;
    if (j < n1)            { src = k; dst = kb; }
    else if (j < 2 * n1)   { src = q; dst = qb; j -= n1; }
    else if (j < 3 * n1)   { src = v; dst = vb; j -= 2 * n1; }
    else                   { src = W; dst = Wb; j -= 3 * n1; }
    const float4 f = ((const float4*)src)[j];
    us4 o;
    o[0] = f2bf(f.x); o[1] = f2bf(f.y); o[2] = f2bf(f.z); o[3] = f2bf(f.w);
    ((us4*)dst)[j] = o;
  }
}

// ---- shared GEMM tile machinery (128x128 tile, BK=32, 4 waves) ----
// LDS rows are 64B (32 bf16); XOR-swizzle (row&3)<<4 on the 16B slot, applied
// as pre-swizzled global source (gload_lds dest stays linear) + swizzled read.

// Fused K/Q/V projection: grid (8, 96). y>>5 selects tensor; y&31 = m-block.
__global__ __launch_bounds__(256)
void gemm_proj(const unsigned short* __restrict__ kb, const unsigned short* __restrict__ qb,
               const unsigned short* __restrict__ vb, const unsigned short* __restrict__ W,
               const float* __restrict__ bias,
               unsigned short* __restrict__ Kp, unsigned short* __restrict__ Qp,
               unsigned short* __restrict__ Vt)
{
  __shared__ unsigned short lA[2][128 * 32];
  __shared__ unsigned short lB[2][128 * 32];
  const int tid = threadIdx.x;
  const int w = tid >> 6, l = tid & 63;
  const int grp = blockIdx.y >> 5;                 // 0:K 1:Q 2:V
  const unsigned short* A = grp == 0 ? kb : (grp == 1 ? qb : vb);
  const int n0 = blockIdx.x * 128, m0 = (blockIdx.y & 31) * 128;
  const int wr = w >> 1, wc = w & 1;
  const int lg = l >> 4, lc = l & 15;

  f32x4 acc[4][4];
#pragma unroll
  for (int i = 0; i < 4; ++i)
#pragma unroll
    for (int j = 0; j < 4; ++j) acc[i][j] = (f32x4){0.f, 0.f, 0.f, 0.f};

  const int scolb = (((l & 3) ^ ((l >> 2) & 3)) * 16);  // pre-swizzled source slot

  auto stage = [&](int buf, int k0) {
#pragma unroll
    for (int cc = 0; cc < 2; ++cc) {
      const int slot = w * 2 + cc;
      const int row = slot * 16 + (l >> 2);
      gload16(A + (size_t)(m0 + row) * DD + k0 + (scolb >> 1), &lA[buf][slot * 512]);
      gload16(W + (size_t)(n0 + row) * DD + k0 + (scolb >> 1), &lB[buf][slot * 512]);
    }
  };

  stage(0, 0);
  __syncthreads();
  int cur = 0;
#pragma unroll 1
  for (int kt = 0; kt < 32; ++kt) {
    if (kt < 31) stage(cur ^ 1, (kt + 1) * 32);
    const char* la = (const char*)lA[cur];
    const char* lb = (const char*)lB[cur];
    bf16x8 af[4], bfr[4];
#pragma unroll
    for (int mf = 0; mf < 4; ++mf)
      af[mf] = *(const bf16x8*)(la + (wr * 64 + mf * 16 + lc) * 64 + ((lg * 16) ^ ((lc & 3) << 4)));
#pragma unroll
    for (int nf = 0; nf < 4; ++nf)
      bfr[nf] = *(const bf16x8*)(lb + (wc * 64 + nf * 16 + lc) * 64 + ((lg * 16) ^ ((lc & 3) << 4)));
#pragma unroll
    for (int mf = 0; mf < 4; ++mf)
#pragma unroll
      for (int nf = 0; nf < 4; ++nf)
        acc[mf][nf] = __builtin_amdgcn_mfma_f32_16x16x32_bf16(af[mf], bfr[nf], acc[mf][nf], 0, 0, 0);
    __syncthreads();
    cur ^= 1;
  }

  const float scale = (grp == 1) ? 0.125f : 1.0f;  // fold 1/sqrt(DK) into Q
#pragma unroll
  for (int nf = 0; nf < 4; ++nf) {
    const int colg = n0 + wc * 64 + nf * 16 + lc;
    const float bv = bias[colg];
#pragma unroll
    for (int mf = 0; mf < 4; ++mf) {
      const int rowg = m0 + wr * 64 + mf * 16 + lg * 4;
      if (grp < 2) {
        unsigned short* C = grp == 0 ? Kp : Qp;
#pragma unroll
        for (int r = 0; r < 4; ++r)
          C[(size_t)(rowg + r) * DD + colg] = f2bf(scale * (acc[mf][nf][r] + bv));
      } else {
        const int bb = rowg >> 11, t = rowg & (TT - 1);
        const int hh = colg >> 6, dk = colg & 63;
        us4 pk;
#pragma unroll
        for (int r = 0; r < 4; ++r) pk[r] = f2bf(acc[mf][nf][r] + bv);
        *(us4*)&Vt[((size_t)((bb * HH + hh) * DKK + dk)) * TT + t] = pk;
      }
    }
  }
}

// Final projection: C(fp32) = A @ W^T + bias
__global__ __launch_bounds__(256)
void gemm_out(const unsigned short* __restrict__ A, const unsigned short* __restrict__ W,
              const float* __restrict__ bias, float* __restrict__ Cf)
{
  __shared__ unsigned short lA[2][128 * 32];
  __shared__ unsigned short lB[2][128 * 32];
  const int tid = threadIdx.x;
  const int w = tid >> 6, l = tid & 63;
  const int n0 = blockIdx.x * 128, m0 = blockIdx.y * 128;
  const int wr = w >> 1, wc = w & 1;
  const int lg = l >> 4, lc = l & 15;

  f32x4 acc[4][4];
#pragma unroll
  for (int i = 0; i < 4; ++i)
#pragma unroll
    for (int j = 0; j < 4; ++j) acc[i][j] = (f32x4){0.f, 0.f, 0.f, 0.f};

  const int scolb = (((l & 3) ^ ((l >> 2) & 3)) * 16);

  auto stage = [&](int buf, int k0) {
#pragma unroll
    for (int cc = 0; cc < 2; ++cc) {
      const int slot = w * 2 + cc;
      const int row = slot * 16 + (l >> 2);
      gload16(A + (size_t)(m0 + row) * DD + k0 + (scolb >> 1), &lA[buf][slot * 512]);
      gload16(W + (size_t)(n0 + row) * DD + k0 + (scolb >> 1), &lB[buf][slot * 512]);
    }
  };

  stage(0, 0);
  __syncthreads();
  int cur = 0;
#pragma unroll 1
  for (int kt = 0; kt < 32; ++kt) {
    if (kt < 31) stage(cur ^ 1, (kt + 1) * 32);
    const char* la = (const char*)lA[cur];
    const char* lb = (const char*)lB[cur];
    bf16x8 af[4], bfr[4];
#pragma unroll
    for (int mf = 0; mf < 4; ++mf)
      af[mf] = *(const bf16x8*)(la + (wr * 64 + mf * 16 + lc) * 64 + ((lg * 16) ^ ((lc & 3) << 4)));
#pragma unroll
    for (int nf = 0; nf < 4; ++nf)
      bfr[nf] = *(const bf16x8*)(lb + (wc * 64 + nf * 16 + lc) * 64 + ((lg * 16) ^ ((lc & 3) << 4)));
#pragma unroll
    for (int mf = 0; mf < 4; ++mf)
#pragma unroll
      for (int nf = 0; nf < 4; ++nf)
        acc[mf][nf] = __builtin_amdgcn_mfma_f32_16x16x32_bf16(af[mf], bfr[nf], acc[mf][nf], 0, 0, 0);
    __syncthreads();
    cur ^= 1;
  }

#pragma unroll
  for (int nf = 0; nf < 4; ++nf) {
    const int colg = n0 + wc * 64 + nf * 16 + lc;
    const float bv = bias[colg];
#pragma unroll
    for (int mf = 0; mf < 4; ++mf) {
      const int rowg = m0 + wr * 64 + mf * 16 + lg * 4;
#pragma unroll
      for (int r = 0; r < 4; ++r)
        Cf[(size_t)(rowg + r) * DD + colg] = acc[mf][nf][r] + bv;
    }
  }
}

// Flash attention, swapped-operand QK^T, in-register P, 16x16x16 PV.
// Qp/Kp: [B*T][D] bf16 (Q pre-scaled). Vt: [B*H*DK][T] bf16. Oc: [B*T][D] bf16.
// Grid: x = b*16+h (fast), y: qblk = 31-y (heavy blocks dispatch first).
__global__ __launch_bounds__(256)
void attn(const unsigned short* __restrict__ Qp,
          const unsigned short* __restrict__ Kp,
          const unsigned short* __restrict__ Vt,
          const int* __restrict__ maskp,
          const int* __restrict__ causalp,
          unsigned short* __restrict__ Oc)
{
  __shared__ unsigned short Kl[2][64 * 64];
  __shared__ unsigned short Vl[2][64 * 64];
  const int tid = threadIdx.x;
  const int w = tid >> 6, l = tid & 63;
  const int bh = blockIdx.x;
  const int q0 = (31 - blockIdx.y) * 64;
  const int b = bh >> 4, h = bh & 15;
  const int lg = l >> 4, lc = l & 15;
  const int causal = causalp[0];
  const int qr = q0 + w * 16 + lc;          // this lane's q-row

  // Q as B-operand: B[d][q-col]: col=lc -> q-row, d = kk*32 + lg*8 + j
  bf16x8 qf[2];
  {
    const unsigned short* qp = Qp + (size_t)(b * TT + qr) * DD + h * DKK + lg * 8;
    qf[0] = *(const bf16x8*)qp;
    qf[1] = *(const bf16x8*)(qp + 32);
  }
  f32x4 o[4];                                // o[nfo]: rows lg*4+r (q), cols nfo*16+lc (d)
#pragma unroll
  for (int nfo = 0; nfo < 4; ++nfo) o[nfo] = (f32x4){0.f, 0.f, 0.f, 0.f};
  float m = -1e30f, lsum = 0.f;

  const int swz = ((l & 7) ^ (l >> 3)) * 16;  // pre-swizzled source slot (bytes)

  auto stage = [&](int buf, int c0) {
#pragma unroll
    for (int cc = 0; cc < 2; ++cc) {
      const int slot = w * 2 + cc;
      const int rr = slot * 8 + (l >> 3);
      gload16(Kp + (size_t)(b * TT + c0 + rr) * DD + h * DKK + (swz >> 1), &Kl[buf][slot * 512]);
      gload16(Vt + (size_t)((b * HH + h) * DKK + rr) * TT + c0 + (swz >> 1), &Vl[buf][slot * 512]);
    }
  };

  const int ntiles = (causal ? (q0 + 64) : TT) >> 6;
  stage(0, 0);
  __syncthreads();
  int cur = 0;
#pragma unroll 1
  for (int t = 0; t < ntiles; ++t) {
    if (t + 1 < ntiles) stage(cur ^ 1, (t + 1) * 64);
    const int c0 = t * 64;
    const char* kl = (const char*)Kl[cur];
    const char* vl = (const char*)Vl[cur];

    // S^T = mfma(K, Q): s[nf] covers k-cols nf*16 + lg*4 + r for q-row lc
    f32x4 s[4];
#pragma unroll
    for (int nf = 0; nf < 4; ++nf) s[nf] = (f32x4){0.f, 0.f, 0.f, 0.f};
#pragma unroll
    for (int nf = 0; nf < 4; ++nf)
#pragma unroll
      for (int kk = 0; kk < 2; ++kk) {
        bf16x8 kf = *(const bf16x8*)(kl + (nf * 16 + lc) * 128 + ((kk * 64 + lg * 16) ^ ((lc & 7) << 4)));
        s[nf] = __builtin_amdgcn_mfma_f32_16x16x32_bf16(kf, qf[kk], s[nf], 0, 0, 0);
      }

    // mask (k-side padding + causal)
#pragma unroll
    for (int nf = 0; nf < 4; ++nf) {
      const int4 mv = *(const int4*)&maskp[b * TT + c0 + nf * 16 + lg * 4];
      const int mvr[4] = {mv.x, mv.y, mv.z, mv.w};
#pragma unroll
      for (int r = 0; r < 4; ++r) {
        const int kg = c0 + nf * 16 + lg * 4 + r;
        if ((mvr[r] == 0) || (causal && (kg > qr))) s[nf][r] = -1e30f;
      }
    }

    // online softmax, scalar per lane (q-row = lc); reduce over lg via 2 shuffles
    float pm = s[0][0];
#pragma unroll
    for (int nf = 0; nf < 4; ++nf)
#pragma unroll
      for (int r = 0; r < 4; ++r) pm = fmaxf(pm, s[nf][r]);
    pm = fmaxf(pm, __shfl_xor(pm, 16, 64));
    pm = fmaxf(pm, __shfl_xor(pm, 32, 64));
    const float mn = fmaxf(m, pm);
    const float al = __expf(m - mn);
    m = mn;

    float ps = 0.f;
    bf16x4 pa[4];
#pragma unroll
    for (int nf = 0; nf < 4; ++nf)
#pragma unroll
      for (int r = 0; r < 4; ++r) {
        const float sv = s[nf][r];
        const float p = (sv <= -1e29f) ? 0.f : __expf(sv - m);
        ps += p;
        pa[nf][r] = (short)f2bf(p);
      }
    ps += __shfl_xor(ps, 16, 64);
    ps += __shfl_xor(ps, 32, 64);
    lsum = lsum * al + ps;

    // rescale O: factor for q-row lg*4+r lives in lane (lg*4+r)
    float alr[4];
#pragma unroll
    for (int r = 0; r < 4; ++r) alr[r] = __shfl(al, lg * 4 + r, 64);
#pragma unroll
    for (int nfo = 0; nfo < 4; ++nfo)
#pragma unroll
      for (int r = 0; r < 4; ++r) o[nfo][r] *= alr[r];

    // O += P @ V via 16x16x16: A = pa[nfk] (in-register), B = Vl[d][t]
#pragma unroll
    for (int nfo = 0; nfo < 4; ++nfo)
#pragma unroll
      for (int nfk = 0; nfk < 4; ++nfk) {
        bf16x4 vb = *(const bf16x4*)(vl + (nfo * 16 + lc) * 128 + ((nfk * 32 + lg * 8) ^ ((lc & 7) << 4)));
        o[nfo] = mfma16(pa[nfk], vb, o[nfo]);
      }

    __syncthreads();  // LDS reads of cur done; stage of cur^1 drained
    cur ^= 1;
  }

  // epilogue: l-normalize; lsum for q-row lg*4+r lives in lane (lg*4+r)
  float linv[4];
#pragma unroll
  for (int r = 0; r < 4; ++r) linv[r] = 1.0f / __shfl(lsum, lg * 4 + r, 64);
#pragma unroll
  for (int nfo = 0; nfo < 4; ++nfo) {
    const int dg = h * DKK + nfo * 16 + lc;
#pragma unroll
    for (int r = 0; r < 4; ++r) {
      const int qg = q0 + w * 16 + lg * 4 + r;
      Oc[(size_t)(b * TT + qg) * DD + dg] = f2bf(o[nfo][r] * linv[r]);
    }
  }
}

extern "C" void kernel_launch(void* const* d_in, const int* in_sizes, int n_in,
                              void* d_out, int out_size, void* d_ws, size_t ws_size,
                              hipStream_t stream)
{
  (void)in_sizes; (void)n_in; (void)out_size; (void)ws_size;
  const float* kf = (const float*)d_in[0];
  const float* qf = (const float*)d_in[1];
  const float* vf = (const float*)d_in[2];
  const int* mask = (const int*)d_in[3];
  const int* causal = (const int*)d_in[4];
  const float* Wf = (const float*)d_in[5];
  const float* bf = (const float*)d_in[6];

  const size_t MB = 1024 * 1024;
  char* ws = (char*)d_ws;
  unsigned short* kb = (unsigned short*)(ws);                 // 8 MiB
  unsigned short* qb = (unsigned short*)(ws + 8 * MB);        // 8 MiB
  unsigned short* vb = (unsigned short*)(ws + 16 * MB);       // 8 MiB
  unsigned short* Wb = (unsigned short*)(ws + 24 * MB);       // 2 MiB
  unsigned short* Kp = (unsigned short*)(ws + 26 * MB);       // 8 MiB
  unsigned short* Qp = (unsigned short*)(ws + 34 * MB);       // 8 MiB
  unsigned short* Vt = (unsigned short*)(ws + 42 * MB);       // 8 MiB
  unsigned short* Oc = kb;  // kb dead after projections

  f2b_all<<<dim3(2048), dim3(256), 0, stream>>>(kf, qf, vf, Wf, kb, qb, vb, Wb);
  gemm_proj<<<dim3(8, 96), dim3(256), 0, stream>>>(kb, qb, vb, Wb, bf, Kp, Qp, Vt);
  attn<<<dim3(32, 32), dim3(256), 0, stream>>>(Qp, Kp, Vt, mask, causal, Oc);
  gemm_out<<<dim3(8, 32), dim3(256), 0, stream>>>(Oc, Wb, bf, (float*)d_out);
}

// Round 5
// 144.318 us; speedup vs baseline: 1.8916x; 1.1445x over previous
//
#include <hip/hip_runtime.h>

#define TT 2048
#define DD 1024
#define HH 16
#define DKK 64
#define BB 2

typedef __attribute__((ext_vector_type(8))) short bf16x8;
typedef __attribute__((ext_vector_type(4))) short bf16x4;
typedef __attribute__((ext_vector_type(4))) float f32x4;
typedef __attribute__((ext_vector_type(4))) unsigned short us4;

__device__ __forceinline__ unsigned short f2bf(float f) {
  union { float f; unsigned int i; } v; v.f = f;
  unsigned int x = v.i;
  return (unsigned short)((x + 0x7fffu + ((x >> 16) & 1u)) >> 16);
}
__device__ __forceinline__ unsigned int cvtpk_bf16(float lo, float hi) {
  unsigned int r;
  asm("v_cvt_pk_bf16_f32 %0, %1, %2" : "=v"(r) : "v"(lo), "v"(hi));
  return r;
}
__device__ __forceinline__ void gload16(const void* g, void* l) {
  __builtin_amdgcn_global_load_lds((const __attribute__((address_space(1))) void*)g,
                                   (__attribute__((address_space(3))) void*)l,
                                   16, 0, 0);
}

#if defined(__has_builtin)
#if __has_builtin(__builtin_amdgcn_mfma_f32_16x16x16bf16_1k)
#define HAVE_MFMA16 1
#endif
#endif

__device__ __forceinline__ f32x4 mfma16(bf16x4 a, bf16x4 b, f32x4 c) {
#ifdef HAVE_MFMA16
  return __builtin_amdgcn_mfma_f32_16x16x16bf16_1k(a, b, c, 0, 0, 0);
#else
  asm volatile("v_mfma_f32_16x16x16_bf16 %0, %1, %2, %0\n\ts_nop 7\n\ts_nop 7"
               : "+v"(c) : "v"(a), "v"(b));
  return c;
#endif
}

// fp32 -> bf16 for k,q,v,W in one dispatch
__global__ __launch_bounds__(256)
void f2b_all(const float* __restrict__ k, const float* __restrict__ q,
             const float* __restrict__ v, const float* __restrict__ W,
             unsigned short* __restrict__ kb, unsigned short* __restrict__ qb,
             unsigned short* __restrict__ vb, unsigned short* __restrict__ Wb)
{
  const int n1 = (BB * TT * DD) / 4;   // 1048576 float4s per tensor
  const int nW = (DD * DD) / 4;        // 262144
  const int total = 3 * n1 + nW;
  int i = blockIdx.x * 256 + threadIdx.x;
  const int stride = gridDim.x * 256;
  for (; i < total; i += stride) {
    const float* src; unsigned short* dst; int j = i;
    if (j < n1)            { src = k; dst = kb; }
    else if (j < 2 * n1)   { src = q; dst = qb; j -= n1; }
    else if (j < 3 * n1)   { src = v; dst = vb; j -= 2 * n1; }
    else                   { src = W; dst = Wb; j -= 3 * n1; }
    const float4 f = ((const float4*)src)[j];
    us4 o;
    o[0] = f2bf(f.x); o[1] = f2bf(f.y); o[2] = f2bf(f.z); o[3] = f2bf(f.w);
    ((us4*)dst)[j] = o;
  }
}

// ---- shared GEMM tile machinery (128x128 tile, BK=32, 4 waves) ----
// LDS rows are 64B (32 bf16); XOR-swizzle (row&3)<<4 on the 16B slot, applied
// as pre-swizzled global source (gload_lds dest stays linear) + swizzled read.

// Fused K/Q/V projection: grid (8, 96). y>>5 selects tensor; y&31 = m-block.
__global__ __launch_bounds__(256)
void gemm_proj(const unsigned short* __restrict__ kb, const unsigned short* __restrict__ qb,
               const unsigned short* __restrict__ vb, const unsigned short* __restrict__ W,
               const float* __restrict__ bias,
               unsigned short* __restrict__ Kp, unsigned short* __restrict__ Qp,
               unsigned short* __restrict__ Vt)
{
  __shared__ unsigned short lA[2][128 * 32];
  __shared__ unsigned short lB[2][128 * 32];
  const int tid = threadIdx.x;
  const int w = tid >> 6, l = tid & 63;
  const int grp = blockIdx.y >> 5;                 // 0:K 1:Q 2:V
  const unsigned short* A = grp == 0 ? kb : (grp == 1 ? qb : vb);
  const int n0 = blockIdx.x * 128, m0 = (blockIdx.y & 31) * 128;
  const int wr = w >> 1, wc = w & 1;
  const int lg = l >> 4, lc = l & 15;

  f32x4 acc[4][4];
#pragma unroll
  for (int i = 0; i < 4; ++i)
#pragma unroll
    for (int j = 0; j < 4; ++j) acc[i][j] = (f32x4){0.f, 0.f, 0.f, 0.f};

  const int scolb = (((l & 3) ^ ((l >> 2) & 3)) * 16);  // pre-swizzled source slot

  auto stage = [&](int buf, int k0) {
#pragma unroll
    for (int cc = 0; cc < 2; ++cc) {
      const int slot = w * 2 + cc;
      const int row = slot * 16 + (l >> 2);
      gload16(A + (size_t)(m0 + row) * DD + k0 + (scolb >> 1), &lA[buf][slot * 512]);
      gload16(W + (size_t)(n0 + row) * DD + k0 + (scolb >> 1), &lB[buf][slot * 512]);
    }
  };

  stage(0, 0);
  __syncthreads();
  int cur = 0;
#pragma unroll 1
  for (int kt = 0; kt < 32; ++kt) {
    if (kt < 31) stage(cur ^ 1, (kt + 1) * 32);
    const char* la = (const char*)lA[cur];
    const char* lb = (const char*)lB[cur];
    bf16x8 af[4], bfr[4];
#pragma unroll
    for (int mf = 0; mf < 4; ++mf)
      af[mf] = *(const bf16x8*)(la + (wr * 64 + mf * 16 + lc) * 64 + ((lg * 16) ^ ((lc & 3) << 4)));
#pragma unroll
    for (int nf = 0; nf < 4; ++nf)
      bfr[nf] = *(const bf16x8*)(lb + (wc * 64 + nf * 16 + lc) * 64 + ((lg * 16) ^ ((lc & 3) << 4)));
#pragma unroll
    for (int mf = 0; mf < 4; ++mf)
#pragma unroll
      for (int nf = 0; nf < 4; ++nf)
        acc[mf][nf] = __builtin_amdgcn_mfma_f32_16x16x32_bf16(af[mf], bfr[nf], acc[mf][nf], 0, 0, 0);
    __syncthreads();
    cur ^= 1;
  }

  const float scale = (grp == 1) ? 0.125f : 1.0f;  // fold 1/sqrt(DK) into Q
#pragma unroll
  for (int nf = 0; nf < 4; ++nf) {
    const int colg = n0 + wc * 64 + nf * 16 + lc;
    const float bv = bias[colg];
#pragma unroll
    for (int mf = 0; mf < 4; ++mf) {
      const int rowg = m0 + wr * 64 + mf * 16 + lg * 4;
      if (grp < 2) {
        unsigned short* C = grp == 0 ? Kp : Qp;
#pragma unroll
        for (int r = 0; r < 4; ++r)
          C[(size_t)(rowg + r) * DD + colg] = f2bf(scale * (acc[mf][nf][r] + bv));
      } else {
        const int bb = rowg >> 11, t = rowg & (TT - 1);
        const int hh = colg >> 6, dk = colg & 63;
        us4 pk;
#pragma unroll
        for (int r = 0; r < 4; ++r) pk[r] = f2bf(acc[mf][nf][r] + bv);
        *(us4*)&Vt[((size_t)((bb * HH + hh) * DKK + dk)) * TT + t] = pk;
      }
    }
  }
}

// Final projection: C(fp32) = A @ W^T + bias
__global__ __launch_bounds__(256)
void gemm_out(const unsigned short* __restrict__ A, const unsigned short* __restrict__ W,
              const float* __restrict__ bias, float* __restrict__ Cf)
{
  __shared__ unsigned short lA[2][128 * 32];
  __shared__ unsigned short lB[2][128 * 32];
  const int tid = threadIdx.x;
  const int w = tid >> 6, l = tid & 63;
  const int n0 = blockIdx.x * 128, m0 = blockIdx.y * 128;
  const int wr = w >> 1, wc = w & 1;
  const int lg = l >> 4, lc = l & 15;

  f32x4 acc[4][4];
#pragma unroll
  for (int i = 0; i < 4; ++i)
#pragma unroll
    for (int j = 0; j < 4; ++j) acc[i][j] = (f32x4){0.f, 0.f, 0.f, 0.f};

  const int scolb = (((l & 3) ^ ((l >> 2) & 3)) * 16);

  auto stage = [&](int buf, int k0) {
#pragma unroll
    for (int cc = 0; cc < 2; ++cc) {
      const int slot = w * 2 + cc;
      const int row = slot * 16 + (l >> 2);
      gload16(A + (size_t)(m0 + row) * DD + k0 + (scolb >> 1), &lA[buf][slot * 512]);
      gload16(W + (size_t)(n0 + row) * DD + k0 + (scolb >> 1), &lB[buf][slot * 512]);
    }
  };

  stage(0, 0);
  __syncthreads();
  int cur = 0;
#pragma unroll 1
  for (int kt = 0; kt < 32; ++kt) {
    if (kt < 31) stage(cur ^ 1, (kt + 1) * 32);
    const char* la = (const char*)lA[cur];
    const char* lb = (const char*)lB[cur];
    bf16x8 af[4], bfr[4];
#pragma unroll
    for (int mf = 0; mf < 4; ++mf)
      af[mf] = *(const bf16x8*)(la + (wr * 64 + mf * 16 + lc) * 64 + ((lg * 16) ^ ((lc & 3) << 4)));
#pragma unroll
    for (int nf = 0; nf < 4; ++nf)
      bfr[nf] = *(const bf16x8*)(lb + (wc * 64 + nf * 16 + lc) * 64 + ((lg * 16) ^ ((lc & 3) << 4)));
#pragma unroll
    for (int mf = 0; mf < 4; ++mf)
#pragma unroll
      for (int nf = 0; nf < 4; ++nf)
        acc[mf][nf] = __builtin_amdgcn_mfma_f32_16x16x32_bf16(af[mf], bfr[nf], acc[mf][nf], 0, 0, 0);
    __syncthreads();
    cur ^= 1;
  }

#pragma unroll
  for (int nf = 0; nf < 4; ++nf) {
    const int colg = n0 + wc * 64 + nf * 16 + lc;
    const float bv = bias[colg];
#pragma unroll
    for (int mf = 0; mf < 4; ++mf) {
      const int rowg = m0 + wr * 64 + mf * 16 + lg * 4;
#pragma unroll
      for (int r = 0; r < 4; ++r)
        Cf[(size_t)(rowg + r) * DD + colg] = acc[mf][nf][r] + bv;
    }
  }
}

// Flash attention, swapped-operand QK^T, in-register P, 16x16x16 PV.
// Qp/Kp: [B*T][D] bf16 (Q pre-scaled). Vt: [B*H*DK][T] bf16. Oc: [B*T][D] bf16.
// Grid: x = b*16+h (fast), y: qblk = 31-y (heavy blocks dispatch first).
__global__ __launch_bounds__(256)
void attn(const unsigned short* __restrict__ Qp,
          const unsigned short* __restrict__ Kp,
          const unsigned short* __restrict__ Vt,
          const int* __restrict__ maskp,
          const int* __restrict__ causalp,
          unsigned short* __restrict__ Oc)
{
  __shared__ unsigned short Kl[2][64 * 64];
  __shared__ unsigned short Vl[2][64 * 64];
  const int tid = threadIdx.x;
  const int w = tid >> 6, l = tid & 63;
  const int bh = blockIdx.x;
  const int q0 = (31 - blockIdx.y) * 64;
  const int b = bh >> 4, h = bh & 15;
  const int lg = l >> 4, lc = l & 15;
  const int causal = causalp[0];
  const int qr = q0 + w * 16 + lc;          // this lane's q-row

  // Q as B-operand: col=lc -> q-row, d = kk*32 + lg*8 + j
  bf16x8 qf[2];
  {
    const unsigned short* qp = Qp + (size_t)(b * TT + qr) * DD + h * DKK + lg * 8;
    qf[0] = *(const bf16x8*)qp;
    qf[1] = *(const bf16x8*)(qp + 32);
  }
  f32x4 o[4];                                // o[nfo]: rows lg*4+r (q), cols nfo*16+lc (d)
#pragma unroll
  for (int nfo = 0; nfo < 4; ++nfo) o[nfo] = (f32x4){0.f, 0.f, 0.f, 0.f};
  float m = -1e30f, lsum = 0.f;

  const int swz = ((l & 7) ^ (l >> 3)) * 16;  // pre-swizzled source slot (bytes)

  auto stage = [&](int buf, int c0) {
#pragma unroll
    for (int cc = 0; cc < 2; ++cc) {
      const int slot = w * 2 + cc;
      const int rr = slot * 8 + (l >> 3);
      gload16(Kp + (size_t)(b * TT + c0 + rr) * DD + h * DKK + (swz >> 1), &Kl[buf][slot * 512]);
      gload16(Vt + (size_t)((b * HH + h) * DKK + rr) * TT + c0 + (swz >> 1), &Vl[buf][slot * 512]);
    }
  };

  const int ntiles = (causal ? (q0 + 64) : TT) >> 6;
  stage(0, 0);
  __syncthreads();
  int cur = 0;
#pragma unroll 1
  for (int t = 0; t < ntiles; ++t) {
    if (t + 1 < ntiles) stage(cur ^ 1, (t + 1) * 64);
    const int c0 = t * 64;
    const char* kl = (const char*)Kl[cur];
    const char* vl = (const char*)Vl[cur];

    // S^T = mfma(K, Q): s[nf] covers k-cols nf*16 + lg*4 + r for q-row lc
    f32x4 s[4];
#pragma unroll
    for (int nf = 0; nf < 4; ++nf) s[nf] = (f32x4){0.f, 0.f, 0.f, 0.f};
#pragma unroll
    for (int nf = 0; nf < 4; ++nf)
#pragma unroll
      for (int kk = 0; kk < 2; ++kk) {
        bf16x8 kf = *(const bf16x8*)(kl + (nf * 16 + lc) * 128 + ((kk * 64 + lg * 16) ^ ((lc & 7) << 4)));
        s[nf] = __builtin_amdgcn_mfma_f32_16x16x32_bf16(kf, qf[kk], s[nf], 0, 0, 0);
      }

    // padding mask: fast path skips all per-element work when tile fully alive
    const unsigned long long bal = __ballot(maskp[b * TT + c0 + l] != 0);
    if (bal != ~0ull) {
#pragma unroll
      for (int nf = 0; nf < 4; ++nf) {
        const int4 mv = *(const int4*)&maskp[b * TT + c0 + nf * 16 + lg * 4];
        const int mvr[4] = {mv.x, mv.y, mv.z, mv.w};
#pragma unroll
        for (int r = 0; r < 4; ++r)
          if (mvr[r] == 0) s[nf][r] = -1e30f;
      }
    }
    // causal: only the diagonal tile needs compares (earlier tiles: kg < q0 <= qr)
    if (causal && (t == ntiles - 1)) {
#pragma unroll
      for (int nf = 0; nf < 4; ++nf)
#pragma unroll
        for (int r = 0; r < 4; ++r) {
          const int kg = c0 + nf * 16 + lg * 4 + r;
          if (kg > qr) s[nf][r] = -1e30f;
        }
    }

    // online softmax, scalar per lane (q-row = lc); reduce over lg via 2 shuffles
    float pm = s[0][0];
#pragma unroll
    for (int nf = 0; nf < 4; ++nf)
#pragma unroll
      for (int r = 0; r < 4; ++r) pm = fmaxf(pm, s[nf][r]);
    pm = fmaxf(pm, __shfl_xor(pm, 16, 64));
    pm = fmaxf(pm, __shfl_xor(pm, 32, 64));
    // -1e28 floor keeps exp-underflow masking consistent even for all-dead tiles
    const float mn = fmaxf(fmaxf(m, pm), -1e28f);
    const float al = __expf(m - mn);
    m = mn;

    // P = exp(S - m): dead elements (-1e30) underflow to 0 — no compares needed
    float ps = 0.f;
    bf16x4 pa[4];
#pragma unroll
    for (int nf = 0; nf < 4; ++nf) {
      float p0 = __expf(s[nf][0] - m);
      float p1 = __expf(s[nf][1] - m);
      float p2 = __expf(s[nf][2] - m);
      float p3 = __expf(s[nf][3] - m);
      ps += (p0 + p1) + (p2 + p3);
      union { unsigned int u[2]; bf16x4 v; } pk;
      pk.u[0] = cvtpk_bf16(p0, p1);
      pk.u[1] = cvtpk_bf16(p2, p3);
      pa[nf] = pk.v;
    }
    ps += __shfl_xor(ps, 16, 64);
    ps += __shfl_xor(ps, 32, 64);
    lsum = lsum * al + ps;

    // rescale O: factor for q-row lg*4+r lives in lane (lg*4+r)
    float alr[4];
#pragma unroll
    for (int r = 0; r < 4; ++r) alr[r] = __shfl(al, lg * 4 + r, 64);
#pragma unroll
    for (int nfo = 0; nfo < 4; ++nfo)
#pragma unroll
      for (int r = 0; r < 4; ++r) o[nfo][r] *= alr[r];

    // O += P @ V via 16x16x16: A = pa[nfk] (in-register), B = Vl[d][t]
#pragma unroll
    for (int nfo = 0; nfo < 4; ++nfo)
#pragma unroll
      for (int nfk = 0; nfk < 4; ++nfk) {
        bf16x4 vb = *(const bf16x4*)(vl + (nfo * 16 + lc) * 128 + ((nfk * 32 + lg * 8) ^ ((lc & 7) << 4)));
        o[nfo] = mfma16(pa[nfk], vb, o[nfo]);
      }

    __syncthreads();  // LDS reads of cur done; stage of cur^1 drained
    cur ^= 1;
  }

  // epilogue: l-normalize; lsum for q-row lg*4+r lives in lane (lg*4+r)
  float linv[4];
#pragma unroll
  for (int r = 0; r < 4; ++r) linv[r] = 1.0f / __shfl(lsum, lg * 4 + r, 64);
#pragma unroll
  for (int nfo = 0; nfo < 4; ++nfo) {
    const int dg = h * DKK + nfo * 16 + lc;
#pragma unroll
    for (int r = 0; r < 4; ++r) {
      const int qg = q0 + w * 16 + lg * 4 + r;
      Oc[(size_t)(b * TT + qg) * DD + dg] = f2bf(o[nfo][r] * linv[r]);
    }
  }
}

extern "C" void kernel_launch(void* const* d_in, const int* in_sizes, int n_in,
                              void* d_out, int out_size, void* d_ws, size_t ws_size,
                              hipStream_t stream)
{
  (void)in_sizes; (void)n_in; (void)out_size; (void)ws_size;
  const float* kf = (const float*)d_in[0];
  const float* qf = (const float*)d_in[1];
  const float* vf = (const float*)d_in[2];
  const int* mask = (const int*)d_in[3];
  const int* causal = (const int*)d_in[4];
  const float* Wf = (const float*)d_in[5];
  const float* bf = (const float*)d_in[6];

  const size_t MB = 1024 * 1024;
  char* ws = (char*)d_ws;
  unsigned short* kb = (unsigned short*)(ws);                 // 8 MiB
  unsigned short* qb = (unsigned short*)(ws + 8 * MB);        // 8 MiB
  unsigned short* vb = (unsigned short*)(ws + 16 * MB);       // 8 MiB
  unsigned short* Wb = (unsigned short*)(ws + 24 * MB);       // 2 MiB
  unsigned short* Kp = (unsigned short*)(ws + 26 * MB);       // 8 MiB
  unsigned short* Qp = (unsigned short*)(ws + 34 * MB);       // 8 MiB
  unsigned short* Vt = (unsigned short*)(ws + 42 * MB);       // 8 MiB
  unsigned short* Oc = kb;  // kb dead after projections

  f2b_all<<<dim3(2048), dim3(256), 0, stream>>>(kf, qf, vf, Wf, kb, qb, vb, Wb);
  gemm_proj<<<dim3(8, 96), dim3(256), 0, stream>>>(kb, qb, vb, Wb, bf, Kp, Qp, Vt);
  attn<<<dim3(32, 32), dim3(256), 0, stream>>>(Qp, Kp, Vt, mask, causal, Oc);
  gemm_out<<<dim3(8, 32), dim3(256), 0, stream>>>(Oc, Wb, bf, (float*)d_out);
}

// Round 7
// 143.369 us; speedup vs baseline: 1.9042x; 1.0066x over previous
//
#include <hip/hip_runtime.h>

#define TT 2048
#define DD 1024
#define HH 16
#define DKK 64
#define BB 2

typedef __attribute__((ext_vector_type(8))) short bf16x8;
typedef __attribute__((ext_vector_type(4))) short bf16x4;
typedef __attribute__((ext_vector_type(4))) float f32x4;
typedef __attribute__((ext_vector_type(4))) unsigned short us4;

__device__ __forceinline__ unsigned short f2bf(float f) {
  union { float f; unsigned int i; } v; v.f = f;
  unsigned int x = v.i;
  return (unsigned short)((x + 0x7fffu + ((x >> 16) & 1u)) >> 16);
}
__device__ __forceinline__ unsigned int cvtpk_bf16(float lo, float hi) {
  unsigned int r;
  asm("v_cvt_pk_bf16_f32 %0, %1, %2" : "=v"(r) : "v"(lo), "v"(hi));
  return r;
}
__device__ __forceinline__ void gload16(const void* g, void* l) {
  __builtin_amdgcn_global_load_lds((const __attribute__((address_space(1))) void*)g,
                                   (__attribute__((address_space(3))) void*)l,
                                   16, 0, 0);
}

#if defined(__has_builtin)
#if __has_builtin(__builtin_amdgcn_exp2f)
#define HAVE_EXP2 1
#endif
#if __has_builtin(__builtin_amdgcn_mfma_f32_16x16x16bf16_1k)
#define HAVE_MFMA16 1
#endif
#endif

__device__ __forceinline__ float fexp2(float x) {
#ifdef HAVE_EXP2
  return __builtin_amdgcn_exp2f(x);
#else
  return __builtin_exp2f(x);
#endif
}

__device__ __forceinline__ f32x4 mfma16(bf16x4 a, bf16x4 b, f32x4 c) {
#ifdef HAVE_MFMA16
  return __builtin_amdgcn_mfma_f32_16x16x16bf16_1k(a, b, c, 0, 0, 0);
#else
  asm volatile("v_mfma_f32_16x16x16_bf16 %0, %1, %2, %0\n\ts_nop 7\n\ts_nop 7"
               : "+v"(c) : "v"(a), "v"(b));
  return c;
#endif
}

// fp32 -> bf16 for k,q,v,W in one dispatch
__global__ __launch_bounds__(256)
void f2b_all(const float* __restrict__ k, const float* __restrict__ q,
             const float* __restrict__ v, const float* __restrict__ W,
             unsigned short* __restrict__ kb, unsigned short* __restrict__ qb,
             unsigned short* __restrict__ vb, unsigned short* __restrict__ Wb)
{
  const int n1 = (BB * TT * DD) / 4;   // 1048576 float4s per tensor
  const int nW = (DD * DD) / 4;        // 262144
  const int total = 3 * n1 + nW;
  int i = blockIdx.x * 256 + threadIdx.x;
  const int stride = gridDim.x * 256;
  for (; i < total; i += stride) {
    const float* src; unsigned short* dst; int j = i;
    if (j < n1)            { src = k; dst = kb; }
    else if (j < 2 * n1)   { src = q; dst = qb; j -= n1; }
    else if (j < 3 * n1)   { src = v; dst = vb; j -= 2 * n1; }
    else                   { src = W; dst = Wb; j -= 3 * n1; }
    const float4 f = ((const float4*)src)[j];
    us4 o;
    o[0] = f2bf(f.x); o[1] = f2bf(f.y); o[2] = f2bf(f.z); o[3] = f2bf(f.w);
    ((us4*)dst)[j] = o;
  }
}

// ---- shared GEMM tile machinery (128x128 tile, BK=32, 4 waves) ----
// LDS rows are 64B (32 bf16); XOR-swizzle (row&3)<<4 on the 16B slot, applied
// as pre-swizzled global source (gload_lds dest stays linear) + swizzled read.

// Fused K/Q/V projection: grid (8, 96). y>>5 selects tensor; y&31 = m-block.
__global__ __launch_bounds__(256)
void gemm_proj(const unsigned short* __restrict__ kb, const unsigned short* __restrict__ qb,
               const unsigned short* __restrict__ vb, const unsigned short* __restrict__ W,
               const float* __restrict__ bias,
               unsigned short* __restrict__ Kp, unsigned short* __restrict__ Qp,
               unsigned short* __restrict__ Vt)
{
  __shared__ unsigned short lA[2][128 * 32];
  __shared__ unsigned short lB[2][128 * 32];
  const int tid = threadIdx.x;
  const int w = tid >> 6, l = tid & 63;
  const int grp = blockIdx.y >> 5;                 // 0:K 1:Q 2:V
  const unsigned short* A = grp == 0 ? kb : (grp == 1 ? qb : vb);
  const int n0 = blockIdx.x * 128, m0 = (blockIdx.y & 31) * 128;
  const int wr = w >> 1, wc = w & 1;
  const int lg = l >> 4, lc = l & 15;

  f32x4 acc[4][4];
#pragma unroll
  for (int i = 0; i < 4; ++i)
#pragma unroll
    for (int j = 0; j < 4; ++j) acc[i][j] = (f32x4){0.f, 0.f, 0.f, 0.f};

  const int scolb = (((l & 3) ^ ((l >> 2) & 3)) * 16);  // pre-swizzled source slot

  auto stage = [&](int buf, int k0) {
#pragma unroll
    for (int cc = 0; cc < 2; ++cc) {
      const int slot = w * 2 + cc;
      const int row = slot * 16 + (l >> 2);
      gload16(A + (size_t)(m0 + row) * DD + k0 + (scolb >> 1), &lA[buf][slot * 512]);
      gload16(W + (size_t)(n0 + row) * DD + k0 + (scolb >> 1), &lB[buf][slot * 512]);
    }
  };

  stage(0, 0);
  __syncthreads();
  int cur = 0;
#pragma unroll 1
  for (int kt = 0; kt < 32; ++kt) {
    if (kt < 31) stage(cur ^ 1, (kt + 1) * 32);
    const char* la = (const char*)lA[cur];
    const char* lb = (const char*)lB[cur];
    bf16x8 af[4], bfr[4];
#pragma unroll
    for (int mf = 0; mf < 4; ++mf)
      af[mf] = *(const bf16x8*)(la + (wr * 64 + mf * 16 + lc) * 64 + ((lg * 16) ^ ((lc & 3) << 4)));
#pragma unroll
    for (int nf = 0; nf < 4; ++nf)
      bfr[nf] = *(const bf16x8*)(lb + (wc * 64 + nf * 16 + lc) * 64 + ((lg * 16) ^ ((lc & 3) << 4)));
#pragma unroll
    for (int mf = 0; mf < 4; ++mf)
#pragma unroll
      for (int nf = 0; nf < 4; ++nf)
        acc[mf][nf] = __builtin_amdgcn_mfma_f32_16x16x32_bf16(af[mf], bfr[nf], acc[mf][nf], 0, 0, 0);
    __syncthreads();
    cur ^= 1;
  }

  // Q gets 1/sqrt(DK) * log2(e) folded in (attn softmax runs in exp2 domain)
  const float scale = (grp == 1) ? 0.125f * 1.4426950408889634f : 1.0f;
#pragma unroll
  for (int nf = 0; nf < 4; ++nf) {
    const int colg = n0 + wc * 64 + nf * 16 + lc;
    const float bv = bias[colg];
#pragma unroll
    for (int mf = 0; mf < 4; ++mf) {
      const int rowg = m0 + wr * 64 + mf * 16 + lg * 4;
      if (grp < 2) {
        unsigned short* C = grp == 0 ? Kp : Qp;
#pragma unroll
        for (int r = 0; r < 4; ++r)
          C[(size_t)(rowg + r) * DD + colg] = f2bf(scale * (acc[mf][nf][r] + bv));
      } else {
        const int bb = rowg >> 11, t = rowg & (TT - 1);
        const int hh = colg >> 6, dk = colg & 63;
        us4 pk;
#pragma unroll
        for (int r = 0; r < 4; ++r) pk[r] = f2bf(acc[mf][nf][r] + bv);
        *(us4*)&Vt[((size_t)((bb * HH + hh) * DKK + dk)) * TT + t] = pk;
      }
    }
  }
}

// Final projection: C(fp32) = A @ W^T + bias
__global__ __launch_bounds__(256)
void gemm_out(const unsigned short* __restrict__ A, const unsigned short* __restrict__ W,
              const float* __restrict__ bias, float* __restrict__ Cf)
{
  __shared__ unsigned short lA[2][128 * 32];
  __shared__ unsigned short lB[2][128 * 32];
  const int tid = threadIdx.x;
  const int w = tid >> 6, l = tid & 63;
  const int n0 = blockIdx.x * 128, m0 = blockIdx.y * 128;
  const int wr = w >> 1, wc = w & 1;
  const int lg = l >> 4, lc = l & 15;

  f32x4 acc[4][4];
#pragma unroll
  for (int i = 0; i < 4; ++i)
#pragma unroll
    for (int j = 0; j < 4; ++j) acc[i][j] = (f32x4){0.f, 0.f, 0.f, 0.f};

  const int scolb = (((l & 3) ^ ((l >> 2) & 3)) * 16);

  auto stage = [&](int buf, int k0) {
#pragma unroll
    for (int cc = 0; cc < 2; ++cc) {
      const int slot = w * 2 + cc;
      const int row = slot * 16 + (l >> 2);
      gload16(A + (size_t)(m0 + row) * DD + k0 + (scolb >> 1), &lA[buf][slot * 512]);
      gload16(W + (size_t)(n0 + row) * DD + k0 + (scolb >> 1), &lB[buf][slot * 512]);
    }
  };

  stage(0, 0);
  __syncthreads();
  int cur = 0;
#pragma unroll 1
  for (int kt = 0; kt < 32; ++kt) {
    if (kt < 31) stage(cur ^ 1, (kt + 1) * 32);
    const char* la = (const char*)lA[cur];
    const char* lb = (const char*)lB[cur];
    bf16x8 af[4], bfr[4];
#pragma unroll
    for (int mf = 0; mf < 4; ++mf)
      af[mf] = *(const bf16x8*)(la + (wr * 64 + mf * 16 + lc) * 64 + ((lg * 16) ^ ((lc & 3) << 4)));
#pragma unroll
    for (int nf = 0; nf < 4; ++nf)
      bfr[nf] = *(const bf16x8*)(lb + (wc * 64 + nf * 16 + lc) * 64 + ((lg * 16) ^ ((lc & 3) << 4)));
#pragma unroll
    for (int mf = 0; mf < 4; ++mf)
#pragma unroll
      for (int nf = 0; nf < 4; ++nf)
        acc[mf][nf] = __builtin_amdgcn_mfma_f32_16x16x32_bf16(af[mf], bfr[nf], acc[mf][nf], 0, 0, 0);
    __syncthreads();
    cur ^= 1;
  }

#pragma unroll
  for (int nf = 0; nf < 4; ++nf) {
    const int colg = n0 + wc * 64 + nf * 16 + lc;
    const float bv = bias[colg];
#pragma unroll
    for (int mf = 0; mf < 4; ++mf) {
      const int rowg = m0 + wr * 64 + mf * 16 + lg * 4;
#pragma unroll
      for (int r = 0; r < 4; ++r)
        Cf[(size_t)(rowg + r) * DD + colg] = acc[mf][nf][r] + bv;
    }
  }
}

// Flash attention, swapped-operand QK^T, in-register P, exp2-domain softmax.
// Qp/Kp: [B*T][D] bf16 (Q pre-scaled by 0.125*log2e). Vt: [B*H*DK][T] bf16.
// Grid: x = b*16+h (fast), y: qblk = 31-y (heavy blocks dispatch first).
__global__ __launch_bounds__(256)
void attn(const unsigned short* __restrict__ Qp,
          const unsigned short* __restrict__ Kp,
          const unsigned short* __restrict__ Vt,
          const int* __restrict__ maskp,
          const int* __restrict__ causalp,
          unsigned short* __restrict__ Oc)
{
  __shared__ unsigned short Kl[2][64 * 64];
  __shared__ unsigned short Vl[2][64 * 64];
  const int tid = threadIdx.x;
  const int w = tid >> 6, l = tid & 63;
  const int bh = blockIdx.x;
  const int q0 = (31 - blockIdx.y) * 64;
  const int b = bh >> 4, h = bh & 15;
  const int lg = l >> 4, lc = l & 15;
  const int causal = causalp[0];
  const int qr = q0 + w * 16 + lc;          // this lane's q-row

  // Q as B-operand: col=lc -> q-row, d = kk*32 + lg*8 + j
  bf16x8 qf[2];
  {
    const unsigned short* qp = Qp + (size_t)(b * TT + qr) * DD + h * DKK + lg * 8;
    qf[0] = *(const bf16x8*)qp;
    qf[1] = *(const bf16x8*)(qp + 32);
  }
  f32x4 o[4];                                // o[nfo]: rows lg*4+r (q), cols nfo*16+lc (d)
#pragma unroll
  for (int nfo = 0; nfo < 4; ++nfo) o[nfo] = (f32x4){0.f, 0.f, 0.f, 0.f};
  float m = -1e30f, lsum = 0.f;

  const int swz = ((l & 7) ^ (l >> 3)) * 16;  // pre-swizzled source slot (bytes)
  // loop-invariant swizzled column offsets (fold per-tile addressing to base+imm)
  int kcoff[2], vcoff[4];
#pragma unroll
  for (int kk = 0; kk < 2; ++kk) kcoff[kk] = (kk * 64 + lg * 16) ^ ((lc & 7) << 4);
#pragma unroll
  for (int nfk = 0; nfk < 4; ++nfk) vcoff[nfk] = (nfk * 32 + lg * 8) ^ ((lc & 7) << 4);
  const int rowb = lc * 128;                  // byte offset of this lane's LDS row
  const int* mrow = maskp + b * TT;

  auto stage = [&](int buf, int c0) {
#pragma unroll
    for (int cc = 0; cc < 2; ++cc) {
      const int slot = w * 2 + cc;
      const int rr = slot * 8 + (l >> 3);
      gload16(Kp + (size_t)(b * TT + c0 + rr) * DD + h * DKK + (swz >> 1), &Kl[buf][slot * 512]);
      gload16(Vt + (size_t)((b * HH + h) * DKK + rr) * TT + c0 + (swz >> 1), &Vl[buf][slot * 512]);
    }
  };

  const int ntiles = (causal ? (q0 + 64) : TT) >> 6;
  stage(0, 0);
  __syncthreads();
  int cur = 0;
#pragma unroll 1
  for (int t = 0; t < ntiles; ++t) {
    if (t + 1 < ntiles) stage(cur ^ 1, (t + 1) * 64);
    const int c0 = t * 64;
    const char* kl = (const char*)Kl[cur];
    const char* vl = (const char*)Vl[cur];

    // S^T = mfma(K, Q): s[nf] covers k-cols nf*16 + lg*4 + r for q-row lc
    f32x4 s[4];
#pragma unroll
    for (int nf = 0; nf < 4; ++nf) s[nf] = (f32x4){0.f, 0.f, 0.f, 0.f};
#pragma unroll
    for (int nf = 0; nf < 4; ++nf)
#pragma unroll
      for (int kk = 0; kk < 2; ++kk) {
        bf16x8 kf = *(const bf16x8*)(kl + rowb + kcoff[kk] + nf * 2048);
        s[nf] = __builtin_amdgcn_mfma_f32_16x16x32_bf16(kf, qf[kk], s[nf], 0, 0, 0);
      }

    // padding mask: fast path skips all per-element work when tile fully alive
    const unsigned long long bal = __ballot(mrow[c0 + l] != 0);
    if (bal != ~0ull) {
#pragma unroll
      for (int nf = 0; nf < 4; ++nf) {
        const int4 mv = *(const int4*)&mrow[c0 + nf * 16 + lg * 4];
        const int mvr[4] = {mv.x, mv.y, mv.z, mv.w};
#pragma unroll
        for (int r = 0; r < 4; ++r)
          if (mvr[r] == 0) s[nf][r] = -1e30f;
      }
    }
    // causal: only the diagonal tile needs compares (earlier tiles: kg < q0 <= qr)
    if (causal && (t == ntiles - 1)) {
#pragma unroll
      for (int nf = 0; nf < 4; ++nf)
#pragma unroll
        for (int r = 0; r < 4; ++r) {
          const int kg = c0 + nf * 16 + lg * 4 + r;
          if (kg > qr) s[nf][r] = -1e30f;
        }
    }

    // tile max (clang fuses nested fmaxf to v_max3), reduce over lg (2 shuffles)
    float pm = fmaxf(fmaxf(fmaxf(s[0][0], s[0][1]), fmaxf(s[0][2], s[0][3])),
                     fmaxf(fmaxf(s[1][0], s[1][1]), fmaxf(s[1][2], s[1][3])));
    pm = fmaxf(pm, fmaxf(fmaxf(fmaxf(s[2][0], s[2][1]), fmaxf(s[2][2], s[2][3])),
                         fmaxf(fmaxf(s[3][0], s[3][1]), fmaxf(s[3][2], s[3][3]))));
    pm = fmaxf(pm, __shfl_xor(pm, 16, 64));
    pm = fmaxf(pm, __shfl_xor(pm, 32, 64));

    // unconditional rescale (round-5 structure, exp2 domain)
    const float mn = fmaxf(fmaxf(m, pm), -1e28f);
    const float al = fexp2(m - mn);
    m = mn;
    float alr[4];
#pragma unroll
    for (int r = 0; r < 4; ++r) alr[r] = __shfl(al, lg * 4 + r, 64);
#pragma unroll
    for (int nfo = 0; nfo < 4; ++nfo)
#pragma unroll
      for (int r = 0; r < 4; ++r) o[nfo][r] *= alr[r];

    // P = exp2(S - m): dead (-1e30) underflows to 0, no compares
    float ps = 0.f;
    bf16x4 pa[4];
#pragma unroll
    for (int nf = 0; nf < 4; ++nf) {
      const float p0 = fexp2(s[nf][0] - m);
      const float p1 = fexp2(s[nf][1] - m);
      const float p2 = fexp2(s[nf][2] - m);
      const float p3 = fexp2(s[nf][3] - m);
      ps += (p0 + p1) + (p2 + p3);
      union { unsigned int u[2]; bf16x4 v; } pk;
      pk.u[0] = cvtpk_bf16(p0, p1);
      pk.u[1] = cvtpk_bf16(p2, p3);
      pa[nf] = pk.v;
    }
    ps += __shfl_xor(ps, 16, 64);
    ps += __shfl_xor(ps, 32, 64);
    lsum = lsum * al + ps;

    // O += P @ V via 16x16x16: A = pa[nfk] (in-register), B = Vl[d][t]
#pragma unroll
    for (int nfo = 0; nfo < 4; ++nfo)
#pragma unroll
      for (int nfk = 0; nfk < 4; ++nfk) {
        bf16x4 vb = *(const bf16x4*)(vl + rowb + vcoff[nfk] + nfo * 2048);
        o[nfo] = mfma16(pa[nfk], vb, o[nfo]);
      }

    __syncthreads();  // LDS reads of cur done; stage of cur^1 drained
    cur ^= 1;
  }

  // epilogue: l-normalize; lsum for q-row lg*4+r lives in lane (lg*4+r)
  float linv[4];
#pragma unroll
  for (int r = 0; r < 4; ++r) linv[r] = 1.0f / __shfl(lsum, lg * 4 + r, 64);
#pragma unroll
  for (int nfo = 0; nfo < 4; ++nfo) {
    const int dg = h * DKK + nfo * 16 + lc;
#pragma unroll
    for (int r = 0; r < 4; ++r) {
      const int qg = q0 + w * 16 + lg * 4 + r;
      Oc[(size_t)(b * TT + qg) * DD + dg] = f2bf(o[nfo][r] * linv[r]);
    }
  }
}

extern "C" void kernel_launch(void* const* d_in, const int* in_sizes, int n_in,
                              void* d_out, int out_size, void* d_ws, size_t ws_size,
                              hipStream_t stream)
{
  (void)in_sizes; (void)n_in; (void)out_size; (void)ws_size;
  const float* kf = (const float*)d_in[0];
  const float* qf = (const float*)d_in[1];
  const float* vf = (const float*)d_in[2];
  const int* mask = (const int*)d_in[3];
  const int* causal = (const int*)d_in[4];
  const float* Wf = (const float*)d_in[5];
  const float* bf = (const float*)d_in[6];

  const size_t MB = 1024 * 1024;
  char* ws = (char*)d_ws;
  unsigned short* kb = (unsigned short*)(ws);                 // 8 MiB
  unsigned short* qb = (unsigned short*)(ws + 8 * MB);        // 8 MiB
  unsigned short* vb = (unsigned short*)(ws + 16 * MB);       // 8 MiB
  unsigned short* Wb = (unsigned short*)(ws + 24 * MB);       // 2 MiB
  unsigned short* Kp = (unsigned short*)(ws + 26 * MB);       // 8 MiB
  unsigned short* Qp = (unsigned short*)(ws + 34 * MB);       // 8 MiB
  unsigned short* Vt = (unsigned short*)(ws + 42 * MB);       // 8 MiB
  unsigned short* Oc = kb;  // kb dead after projections

  f2b_all<<<dim3(2048), dim3(256), 0, stream>>>(kf, qf, vf, Wf, kb, qb, vb, Wb);
  gemm_proj<<<dim3(8, 96), dim3(256), 0, stream>>>(kb, qb, vb, Wb, bf, Kp, Qp, Vt);
  attn<<<dim3(32, 32), dim3(256), 0, stream>>>(Qp, Kp, Vt, mask, causal, Oc);
  gemm_out<<<dim3(8, 32), dim3(256), 0, stream>>>(Oc, Wb, bf, (float*)d_out);
}

// Round 9
// 138.123 us; speedup vs baseline: 1.9765x; 1.0380x over previous
//
#include <hip/hip_runtime.h>

#define TT 2048
#define DD 1024
#define HH 16
#define DKK 64
#define BB 2

typedef __attribute__((ext_vector_type(8))) short bf16x8;
typedef __attribute__((ext_vector_type(4))) short bf16x4;
typedef __attribute__((ext_vector_type(4))) float f32x4;
typedef __attribute__((ext_vector_type(4))) unsigned short us4;

__device__ __forceinline__ unsigned short f2bf(float f) {
  union { float f; unsigned int i; } v; v.f = f;
  unsigned int x = v.i;
  return (unsigned short)((x + 0x7fffu + ((x >> 16) & 1u)) >> 16);
}
__device__ __forceinline__ unsigned int cvtpk_bf16(float lo, float hi) {
  unsigned int r;
  asm("v_cvt_pk_bf16_f32 %0, %1, %2" : "=v"(r) : "v"(lo), "v"(hi));
  return r;
}
__device__ __forceinline__ void gload16(const void* g, void* l) {
  __builtin_amdgcn_global_load_lds((const __attribute__((address_space(1))) void*)g,
                                   (__attribute__((address_space(3))) void*)l,
                                   16, 0, 0);
}

#if defined(__has_builtin)
#if __has_builtin(__builtin_amdgcn_exp2f)
#define HAVE_EXP2 1
#endif
#if __has_builtin(__builtin_amdgcn_mfma_f32_16x16x16bf16_1k)
#define HAVE_MFMA16 1
#endif
#endif

__device__ __forceinline__ float fexp2(float x) {
#ifdef HAVE_EXP2
  return __builtin_amdgcn_exp2f(x);
#else
  return __builtin_exp2f(x);
#endif
}

__device__ __forceinline__ f32x4 mfma16(bf16x4 a, bf16x4 b, f32x4 c) {
#ifdef HAVE_MFMA16
  return __builtin_amdgcn_mfma_f32_16x16x16bf16_1k(a, b, c, 0, 0, 0);
#else
  asm volatile("v_mfma_f32_16x16x16_bf16 %0, %1, %2, %0\n\ts_nop 7\n\ts_nop 7"
               : "+v"(c) : "v"(a), "v"(b));
  return c;
#endif
}

// fp32 -> bf16 for k,q,v,W in one dispatch
__global__ __launch_bounds__(256)
void f2b_all(const float* __restrict__ k, const float* __restrict__ q,
             const float* __restrict__ v, const float* __restrict__ W,
             unsigned short* __restrict__ kb, unsigned short* __restrict__ qb,
             unsigned short* __restrict__ vb, unsigned short* __restrict__ Wb)
{
  const int n1 = (BB * TT * DD) / 4;   // 1048576 float4s per tensor
  const int nW = (DD * DD) / 4;        // 262144
  const int total = 3 * n1 + nW;
  int i = blockIdx.x * 256 + threadIdx.x;
  const int stride = gridDim.x * 256;
  for (; i < total; i += stride) {
    const float* src; unsigned short* dst; int j = i;
    if (j < n1)            { src = k; dst = kb; }
    else if (j < 2 * n1)   { src = q; dst = qb; j -= n1; }
    else if (j < 3 * n1)   { src = v; dst = vb; j -= 2 * n1; }
    else                   { src = W; dst = Wb; j -= 3 * n1; }
    const float4 f = ((const float4*)src)[j];
    us4 o;
    o[0] = f2bf(f.x); o[1] = f2bf(f.y); o[2] = f2bf(f.z); o[3] = f2bf(f.w);
    ((us4*)dst)[j] = o;
  }
}

// ---- shared GEMM tile machinery (128x128 tile, BK=32, 4 waves) ----
// LDS rows are 64B (32 bf16); XOR-swizzle (row&3)<<4 on the 16B slot, applied
// as pre-swizzled global source (gload_lds dest stays linear) + swizzled read.
// Both GEMMs use a bijective XCD swizzle: blocks sharing an A-strip stay on
// one XCD so the strip is fetched once into that XCD's L2 (T1).

// Fused K/Q/V projection: 768 blocks; virt id: n fast (8), m-strip (96) slow.
__global__ __launch_bounds__(256)
void gemm_proj(const unsigned short* __restrict__ kb, const unsigned short* __restrict__ qb,
               const unsigned short* __restrict__ vb, const unsigned short* __restrict__ W,
               const float* __restrict__ bias,
               unsigned short* __restrict__ Kp, unsigned short* __restrict__ Qp,
               unsigned short* __restrict__ Vt)
{
  __shared__ unsigned short lA[2][128 * 32];
  __shared__ unsigned short lB[2][128 * 32];
  const int tid = threadIdx.x;
  const int w = tid >> 6, l = tid & 63;
  // XCD swizzle: hw -> virt so each XCD owns 12 consecutive m-strips
  const int hw = blockIdx.y * gridDim.x + blockIdx.x;     // 0..767
  const int virt = (hw & 7) * 96 + (hw >> 3);
  const int n0 = (virt & 7) * 128;
  const int my = virt >> 3;                                // 0..95
  const int grp = my >> 5;                                 // 0:K 1:Q 2:V
  const int m0 = (my & 31) * 128;
  const unsigned short* A = grp == 0 ? kb : (grp == 1 ? qb : vb);
  const int wr = w >> 1, wc = w & 1;
  const int lg = l >> 4, lc = l & 15;

  f32x4 acc[4][4];
#pragma unroll
  for (int i = 0; i < 4; ++i)
#pragma unroll
    for (int j = 0; j < 4; ++j) acc[i][j] = (f32x4){0.f, 0.f, 0.f, 0.f};

  const int scolb = (((l & 3) ^ ((l >> 2) & 3)) * 16);  // pre-swizzled source slot

  auto stage = [&](int buf, int k0) {
#pragma unroll
    for (int cc = 0; cc < 2; ++cc) {
      const int slot = w * 2 + cc;
      const int row = slot * 16 + (l >> 2);
      gload16(A + (size_t)(m0 + row) * DD + k0 + (scolb >> 1), &lA[buf][slot * 512]);
      gload16(W + (size_t)(n0 + row) * DD + k0 + (scolb >> 1), &lB[buf][slot * 512]);
    }
  };

  stage(0, 0);
  __syncthreads();
  int cur = 0;
#pragma unroll 1
  for (int kt = 0; kt < 32; ++kt) {
    if (kt < 31) stage(cur ^ 1, (kt + 1) * 32);
    const char* la = (const char*)lA[cur];
    const char* lb = (const char*)lB[cur];
    bf16x8 af[4], bfr[4];
#pragma unroll
    for (int mf = 0; mf < 4; ++mf)
      af[mf] = *(const bf16x8*)(la + (wr * 64 + mf * 16 + lc) * 64 + ((lg * 16) ^ ((lc & 3) << 4)));
#pragma unroll
    for (int nf = 0; nf < 4; ++nf)
      bfr[nf] = *(const bf16x8*)(lb + (wc * 64 + nf * 16 + lc) * 64 + ((lg * 16) ^ ((lc & 3) << 4)));
#pragma unroll
    for (int mf = 0; mf < 4; ++mf)
#pragma unroll
      for (int nf = 0; nf < 4; ++nf)
        acc[mf][nf] = __builtin_amdgcn_mfma_f32_16x16x32_bf16(af[mf], bfr[nf], acc[mf][nf], 0, 0, 0);
    __syncthreads();
    cur ^= 1;
  }

  // Q gets 1/sqrt(DK) * log2(e) folded in (attn softmax runs in exp2 domain)
  const float scale = (grp == 1) ? 0.125f * 1.4426950408889634f : 1.0f;
#pragma unroll
  for (int nf = 0; nf < 4; ++nf) {
    const int colg = n0 + wc * 64 + nf * 16 + lc;
    const float bv = bias[colg];
#pragma unroll
    for (int mf = 0; mf < 4; ++mf) {
      const int rowg = m0 + wr * 64 + mf * 16 + lg * 4;
      if (grp < 2) {
        unsigned short* C = grp == 0 ? Kp : Qp;
#pragma unroll
        for (int r = 0; r < 4; ++r)
          C[(size_t)(rowg + r) * DD + colg] = f2bf(scale * (acc[mf][nf][r] + bv));
      } else {
        const int bb = rowg >> 11, t = rowg & (TT - 1);
        const int hh = colg >> 6, dk = colg & 63;
        us4 pk;
#pragma unroll
        for (int r = 0; r < 4; ++r) pk[r] = f2bf(acc[mf][nf][r] + bv);
        *(us4*)&Vt[((size_t)((bb * HH + hh) * DKK + dk)) * TT + t] = pk;
      }
    }
  }
}

// Final projection: C(fp32) = A @ W^T + bias; 256 blocks, XCD-swizzled.
__global__ __launch_bounds__(256)
void gemm_out(const unsigned short* __restrict__ A, const unsigned short* __restrict__ W,
              const float* __restrict__ bias, float* __restrict__ Cf)
{
  __shared__ unsigned short lA[2][128 * 32];
  __shared__ unsigned short lB[2][128 * 32];
  const int tid = threadIdx.x;
  const int w = tid >> 6, l = tid & 63;
  const int hw = blockIdx.y * gridDim.x + blockIdx.x;     // 0..255
  const int virt = (hw & 7) * 32 + (hw >> 3);
  const int n0 = (virt & 7) * 128, m0 = (virt >> 3) * 128;
  const int wr = w >> 1, wc = w & 1;
  const int lg = l >> 4, lc = l & 15;

  f32x4 acc[4][4];
#pragma unroll
  for (int i = 0; i < 4; ++i)
#pragma unroll
    for (int j = 0; j < 4; ++j) acc[i][j] = (f32x4){0.f, 0.f, 0.f, 0.f};

  const int scolb = (((l & 3) ^ ((l >> 2) & 3)) * 16);

  auto stage = [&](int buf, int k0) {
#pragma unroll
    for (int cc = 0; cc < 2; ++cc) {
      const int slot = w * 2 + cc;
      const int row = slot * 16 + (l >> 2);
      gload16(A + (size_t)(m0 + row) * DD + k0 + (scolb >> 1), &lA[buf][slot * 512]);
      gload16(W + (size_t)(n0 + row) * DD + k0 + (scolb >> 1), &lB[buf][slot * 512]);
    }
  };

  stage(0, 0);
  __syncthreads();
  int cur = 0;
#pragma unroll 1
  for (int kt = 0; kt < 32; ++kt) {
    if (kt < 31) stage(cur ^ 1, (kt + 1) * 32);
    const char* la = (const char*)lA[cur];
    const char* lb = (const char*)lB[cur];
    bf16x8 af[4], bfr[4];
#pragma unroll
    for (int mf = 0; mf < 4; ++mf)
      af[mf] = *(const bf16x8*)(la + (wr * 64 + mf * 16 + lc) * 64 + ((lg * 16) ^ ((lc & 3) << 4)));
#pragma unroll
    for (int nf = 0; nf < 4; ++nf)
      bfr[nf] = *(const bf16x8*)(lb + (wc * 64 + nf * 16 + lc) * 64 + ((lg * 16) ^ ((lc & 3) << 4)));
#pragma unroll
    for (int mf = 0; mf < 4; ++mf)
#pragma unroll
      for (int nf = 0; nf < 4; ++nf)
        acc[mf][nf] = __builtin_amdgcn_mfma_f32_16x16x32_bf16(af[mf], bfr[nf], acc[mf][nf], 0, 0, 0);
    __syncthreads();
    cur ^= 1;
  }

#pragma unroll
  for (int nf = 0; nf < 4; ++nf) {
    const int colg = n0 + wc * 64 + nf * 16 + lc;
    const float bv = bias[colg];
#pragma unroll
    for (int mf = 0; mf < 4; ++mf) {
      const int rowg = m0 + wr * 64 + mf * 16 + lg * 4;
#pragma unroll
      for (int r = 0; r < 4; ++r)
        Cf[(size_t)(rowg + r) * DD + colg] = acc[mf][nf][r] + bv;
    }
  }
}

// Flash attention (round-7 known-good version): swapped-operand QK^T,
// in-register P, exp2-domain softmax. QBLK=64, grid (32,32).
// Qp/Kp: [B*T][D] bf16 (Q pre-scaled by 0.125*log2e). Vt: [B*H*DK][T] bf16.
__global__ __launch_bounds__(256)
void attn(const unsigned short* __restrict__ Qp,
          const unsigned short* __restrict__ Kp,
          const unsigned short* __restrict__ Vt,
          const int* __restrict__ maskp,
          const int* __restrict__ causalp,
          unsigned short* __restrict__ Oc)
{
  __shared__ unsigned short Kl[2][64 * 64];
  __shared__ unsigned short Vl[2][64 * 64];
  const int tid = threadIdx.x;
  const int w = tid >> 6, l = tid & 63;
  const int bh = blockIdx.x;
  const int q0 = (31 - blockIdx.y) * 64;
  const int b = bh >> 4, h = bh & 15;
  const int lg = l >> 4, lc = l & 15;
  const int causal = causalp[0];
  const int qr = q0 + w * 16 + lc;          // this lane's q-row

  // Q as B-operand: col=lc -> q-row, d = kk*32 + lg*8 + j
  bf16x8 qf[2];
  {
    const unsigned short* qp = Qp + (size_t)(b * TT + qr) * DD + h * DKK + lg * 8;
    qf[0] = *(const bf16x8*)qp;
    qf[1] = *(const bf16x8*)(qp + 32);
  }
  f32x4 o[4];                                // o[nfo]: rows lg*4+r (q), cols nfo*16+lc (d)
#pragma unroll
  for (int nfo = 0; nfo < 4; ++nfo) o[nfo] = (f32x4){0.f, 0.f, 0.f, 0.f};
  float m = -1e30f, lsum = 0.f;

  const int swz = ((l & 7) ^ (l >> 3)) * 16;  // pre-swizzled source slot (bytes)
  // loop-invariant swizzled column offsets (fold per-tile addressing to base+imm)
  int kcoff[2], vcoff[4];
#pragma unroll
  for (int kk = 0; kk < 2; ++kk) kcoff[kk] = (kk * 64 + lg * 16) ^ ((lc & 7) << 4);
#pragma unroll
  for (int nfk = 0; nfk < 4; ++nfk) vcoff[nfk] = (nfk * 32 + lg * 8) ^ ((lc & 7) << 4);
  const int rowb = lc * 128;                  // byte offset of this lane's LDS row
  const int* mrow = maskp + b * TT;

  auto stage = [&](int buf, int c0) {
#pragma unroll
    for (int cc = 0; cc < 2; ++cc) {
      const int slot = w * 2 + cc;
      const int rr = slot * 8 + (l >> 3);
      gload16(Kp + (size_t)(b * TT + c0 + rr) * DD + h * DKK + (swz >> 1), &Kl[buf][slot * 512]);
      gload16(Vt + (size_t)((b * HH + h) * DKK + rr) * TT + c0 + (swz >> 1), &Vl[buf][slot * 512]);
    }
  };

  const int ntiles = (causal ? (q0 + 64) : TT) >> 6;
  stage(0, 0);
  __syncthreads();
  int cur = 0;
#pragma unroll 1
  for (int t = 0; t < ntiles; ++t) {
    if (t + 1 < ntiles) stage(cur ^ 1, (t + 1) * 64);
    const int c0 = t * 64;
    const char* kl = (const char*)Kl[cur];
    const char* vl = (const char*)Vl[cur];

    // S^T = mfma(K, Q): s[nf] covers k-cols nf*16 + lg*4 + r for q-row lc
    f32x4 s[4];
#pragma unroll
    for (int nf = 0; nf < 4; ++nf) s[nf] = (f32x4){0.f, 0.f, 0.f, 0.f};
#pragma unroll
    for (int nf = 0; nf < 4; ++nf)
#pragma unroll
      for (int kk = 0; kk < 2; ++kk) {
        bf16x8 kf = *(const bf16x8*)(kl + rowb + kcoff[kk] + nf * 2048);
        s[nf] = __builtin_amdgcn_mfma_f32_16x16x32_bf16(kf, qf[kk], s[nf], 0, 0, 0);
      }

    // padding mask: fast path skips all per-element work when tile fully alive
    const unsigned long long bal = __ballot(mrow[c0 + l] != 0);
    if (bal != ~0ull) {
#pragma unroll
      for (int nf = 0; nf < 4; ++nf) {
        const int4 mv = *(const int4*)&mrow[c0 + nf * 16 + lg * 4];
        const int mvr[4] = {mv.x, mv.y, mv.z, mv.w};
#pragma unroll
        for (int r = 0; r < 4; ++r)
          if (mvr[r] == 0) s[nf][r] = -1e30f;
      }
    }
    // causal: only the diagonal tile needs compares (earlier tiles: kg < q0 <= qr)
    if (causal && (t == ntiles - 1)) {
#pragma unroll
      for (int nf = 0; nf < 4; ++nf)
#pragma unroll
        for (int r = 0; r < 4; ++r) {
          const int kg = c0 + nf * 16 + lg * 4 + r;
          if (kg > qr) s[nf][r] = -1e30f;
        }
    }

    // tile max (clang fuses nested fmaxf to v_max3), reduce over lg (2 shuffles)
    float pm = fmaxf(fmaxf(fmaxf(s[0][0], s[0][1]), fmaxf(s[0][2], s[0][3])),
                     fmaxf(fmaxf(s[1][0], s[1][1]), fmaxf(s[1][2], s[1][3])));
    pm = fmaxf(pm, fmaxf(fmaxf(fmaxf(s[2][0], s[2][1]), fmaxf(s[2][2], s[2][3])),
                         fmaxf(fmaxf(s[3][0], s[3][1]), fmaxf(s[3][2], s[3][3]))));
    pm = fmaxf(pm, __shfl_xor(pm, 16, 64));
    pm = fmaxf(pm, __shfl_xor(pm, 32, 64));

    // unconditional rescale (exp2 domain)
    const float mn = fmaxf(fmaxf(m, pm), -1e28f);
    const float al = fexp2(m - mn);
    m = mn;
    float alr[4];
#pragma unroll
    for (int r = 0; r < 4; ++r) alr[r] = __shfl(al, lg * 4 + r, 64);
#pragma unroll
    for (int nfo = 0; nfo < 4; ++nfo)
#pragma unroll
      for (int r = 0; r < 4; ++r) o[nfo][r] *= alr[r];

    // P = exp2(S - m): dead (-1e30) underflows to 0, no compares
    float ps = 0.f;
    bf16x4 pa[4];
#pragma unroll
    for (int nf = 0; nf < 4; ++nf) {
      const float p0 = fexp2(s[nf][0] - m);
      const float p1 = fexp2(s[nf][1] - m);
      const float p2 = fexp2(s[nf][2] - m);
      const float p3 = fexp2(s[nf][3] - m);
      ps += (p0 + p1) + (p2 + p3);
      union { unsigned int u[2]; bf16x4 v; } pk;
      pk.u[0] = cvtpk_bf16(p0, p1);
      pk.u[1] = cvtpk_bf16(p2, p3);
      pa[nf] = pk.v;
    }
    ps += __shfl_xor(ps, 16, 64);
    ps += __shfl_xor(ps, 32, 64);
    lsum = lsum * al + ps;

    // O += P @ V via 16x16x16: A = pa[nfk] (in-register), B = Vl[d][t]
#pragma unroll
    for (int nfo = 0; nfo < 4; ++nfo)
#pragma unroll
      for (int nfk = 0; nfk < 4; ++nfk) {
        bf16x4 vb = *(const bf16x4*)(vl + rowb + vcoff[nfk] + nfo * 2048);
        o[nfo] = mfma16(pa[nfk], vb, o[nfo]);
      }

    __syncthreads();  // LDS reads of cur done; stage of cur^1 drained
    cur ^= 1;
  }

  // epilogue: l-normalize; lsum for q-row lg*4+r lives in lane (lg*4+r)
  float linv[4];
#pragma unroll
  for (int r = 0; r < 4; ++r) linv[r] = 1.0f / __shfl(lsum, lg * 4 + r, 64);
#pragma unroll
  for (int nfo = 0; nfo < 4; ++nfo) {
    const int dg = h * DKK + nfo * 16 + lc;
#pragma unroll
    for (int r = 0; r < 4; ++r) {
      const int qg = q0 + w * 16 + lg * 4 + r;
      Oc[(size_t)(b * TT + qg) * DD + dg] = f2bf(o[nfo][r] * linv[r]);
    }
  }
}

extern "C" void kernel_launch(void* const* d_in, const int* in_sizes, int n_in,
                              void* d_out, int out_size, void* d_ws, size_t ws_size,
                              hipStream_t stream)
{
  (void)in_sizes; (void)n_in; (void)out_size; (void)ws_size;
  const float* kf = (const float*)d_in[0];
  const float* qf = (const float*)d_in[1];
  const float* vf = (const float*)d_in[2];
  const int* mask = (const int*)d_in[3];
  const int* causal = (const int*)d_in[4];
  const float* Wf = (const float*)d_in[5];
  const float* bf = (const float*)d_in[6];

  const size_t MB = 1024 * 1024;
  char* ws = (char*)d_ws;
  unsigned short* kb = (unsigned short*)(ws);                 // 8 MiB
  unsigned short* qb = (unsigned short*)(ws + 8 * MB);        // 8 MiB
  unsigned short* vb = (unsigned short*)(ws + 16 * MB);       // 8 MiB
  unsigned short* Wb = (unsigned short*)(ws + 24 * MB);       // 2 MiB
  unsigned short* Kp = (unsigned short*)(ws + 26 * MB);       // 8 MiB
  unsigned short* Qp = (unsigned short*)(ws + 34 * MB);       // 8 MiB
  unsigned short* Vt = (unsigned short*)(ws + 42 * MB);       // 8 MiB
  unsigned short* Oc = kb;  // kb dead after projections

  f2b_all<<<dim3(2048), dim3(256), 0, stream>>>(kf, qf, vf, Wf, kb, qb, vb, Wb);
  gemm_proj<<<dim3(8, 96), dim3(256), 0, stream>>>(kb, qb, vb, Wb, bf, Kp, Qp, Vt);
  attn<<<dim3(32, 32), dim3(256), 0, stream>>>(Qp, Kp, Vt, mask, causal, Oc);
  gemm_out<<<dim3(8, 32), dim3(256), 0, stream>>>(Oc, Wb, bf, (float*)d_out);
}